// Round 9
// baseline (113.422 us; speedup 1.0000x reference)
//
#include <hip/hip_runtime.h>
#include <hip/hip_bf16.h>

#define BB 8
#define NN 200000
#define CC 10
#define NBINS 16384
#define TOPK 1000
#define CANDN 4096
#define PROPN 200

// ---- Static device scratch (no dependence on ws_size) ----
__device__ unsigned int g_hist[BB * NBINS];
__device__ int g_candCount[BB];
__device__ int g_binB1[BB];
__device__ unsigned int g_smono[(size_t)BB * NN];   // monotone-mapped scores
__device__ unsigned long long g_cand[BB * CANDN];
__device__ unsigned int g_topk[BB * TOPK];
__device__ float g_tb_box[BB * TOPK * 7];
__device__ double g_su[BB * TOPK * 4];
__device__ double g_area[BB * TOPK];
__device__ float g_tb_score[BB * TOPK];
__device__ int g_tb_lab[BB * TOPK];
__device__ int g_tb_dir[BB * TOPK];
__device__ unsigned long long g_mask[BB * TOPK * 16];

__device__ __forceinline__ unsigned int f2mono(float f) {
  unsigned int u = __float_as_uint(f);
  return (u & 0x80000000u) ? ~u : (u | 0x80000000u);
}

// Kernel 1: streaming per-box max logit -> monotone u32. Also zeroes
// g_hist / g_candCount at entry (folded k_init; consumers run later).
#define SCHUNK 1024
__global__ __launch_bounds__(256) void k_score(const float* __restrict__ cls) {
  {
    const int gid = (blockIdx.y * gridDim.x + blockIdx.x) * 256 + threadIdx.x;
    if (gid < BB * NBINS) g_hist[gid] = 0u;
    if (gid < BB) g_candCount[gid] = 0;
  }
  __shared__ float sb[256 * CC];          // 10 KB staging
  const int b = blockIdx.y;
  const int base = blockIdx.x * SCHUNK;
  const float* cp = cls + ((size_t)b * NN + base) * CC;
  const int nbox = min(SCHUNK, NN - base);
  for (int c0 = 0; c0 < nbox; c0 += 256) {
    const int nb = min(256, nbox - c0);      // 256 or 64 (tail): nb*CC % 4 == 0
    const int nf4 = nb * CC / 4;
    const float4* src = (const float4*)(cp + (size_t)c0 * CC);
    for (int i = threadIdx.x; i < nf4; i += 256)
      ((float4*)sb)[i] = src[i];
    __syncthreads();
    if (threadIdx.x < nb) {
      const float2* p = (const float2*)(sb + threadIdx.x * CC);  // 8B-aligned
      float2 v0 = p[0], v1 = p[1], v2 = p[2], v3 = p[3], v4 = p[4];
      float m = fmaxf(fmaxf(fmaxf(v0.x, v0.y), fmaxf(v1.x, v1.y)),
                      fmaxf(fmaxf(v2.x, v2.y),
                            fmaxf(fmaxf(v3.x, v3.y), fmaxf(v4.x, v4.y))));
      g_smono[(size_t)b * NN + base + c0 + threadIdx.x] = f2mono(m);
    }
    __syncthreads();
  }
}

// Kernel 1b: 14-bit-prefix histogram from g_smono (L2-hot, 6.4 MB).
#define HCHUNK 2048
__global__ __launch_bounds__(256) void k_hist() {
  __shared__ unsigned int h[NBINS];       // 64 KB
  for (int i = threadIdx.x; i < NBINS; i += 256) h[i] = 0u;
  __syncthreads();
  const int b = blockIdx.y;
  const int base = blockIdx.x * HCHUNK;
  const int nv = min(HCHUNK, NN - base) / 4;   // all multiples of 4
  const uint4* sp = (const uint4*)(g_smono + (size_t)b * NN + base);
  for (int i = threadIdx.x; i < nv; i += 256) {
    uint4 v = sp[i];
    atomicAdd(&h[v.x >> 18], 1u);
    atomicAdd(&h[v.y >> 18], 1u);
    atomicAdd(&h[v.z >> 18], 1u);
    atomicAdd(&h[v.w >> 18], 1u);
  }
  __syncthreads();
  unsigned int* hg = g_hist + (size_t)b * NBINS;
  for (int i = threadIdx.x; i < NBINS; i += 256)
    if (h[i]) atomicAdd(&hg[i], h[i]);
}

// Kernel 2: find threshold bin (scan from top until cumulative >= TOPK).
__global__ void k_pickbin() {
  const int b = blockIdx.x;
  __shared__ unsigned int csum[256];
  const unsigned int* h = g_hist + (size_t)b * NBINS;
  unsigned int s = 0;
  const int c0 = threadIdx.x * 64;
  for (int i = 0; i < 64; i++) s += h[c0 + i];
  csum[threadIdx.x] = s;
  __syncthreads();
  if (threadIdx.x == 0) {
    unsigned int cum = 0; int bin = 0; bool done = false;
    for (int cc = 255; cc >= 0 && !done; cc--) {
      if (cum + csum[cc] >= (unsigned)TOPK) {
        for (int i = 63; i >= 0; i--) {
          unsigned int v = h[cc * 64 + i];
          if (cum + v >= (unsigned)TOPK) { bin = cc * 64 + i; done = true; break; }
          cum += v;
        }
      } else {
        cum += csum[cc];
      }
    }
    g_binB1[b] = bin;
  }
}

// Kernel 3: compact candidates. Per-block LDS buffer + ONE global atomic/block.
__global__ __launch_bounds__(256) void k_compact() {
  __shared__ unsigned long long lbuf[SCHUNK];   // 8 KB (chunk <= 1024 cands)
  __shared__ int lcnt, lbase;
  if (threadIdx.x == 0) lcnt = 0;
  __syncthreads();
  const int b = blockIdx.y;
  const int base = blockIdx.x * SCHUNK;
  const int B1 = g_binB1[b];
  const int lim = min(base + SCHUNK, NN);
  for (int n = base + threadIdx.x; n < lim; n += 256) {
    unsigned int mono = g_smono[(size_t)b * NN + n];
    if ((int)(mono >> 18) >= B1) {
      int p = atomicAdd(&lcnt, 1);
      lbuf[p] = ((unsigned long long)(~mono) << 32) | (unsigned int)n;
    }
  }
  __syncthreads();
  if (threadIdx.x == 0) {
    lbase = atomicAdd(&g_candCount[b], lcnt);
  }
  __syncthreads();
  const int c = lcnt, gb = lbase;
  for (int i = threadIdx.x; i < c; i += 256) {
    int pos = gb + i;
    if (pos < CANDN) g_cand[(size_t)b * CANDN + pos] = lbuf[i];
  }
}

// Kernel 4: all-pairs RANK select. rank(x) = #{keys < x}; keys unique ->
// exact permutation; rank<TOPK => g_topk[rank]=idx ((score desc, idx asc)).
__global__ __launch_bounds__(256) void k_rank() {
  __shared__ unsigned long long tile[256];   // 2 KB
  const int b = blockIdx.y;
  const int cnt = min(g_candCount[b], CANDN);
  const int base = blockIdx.x * 256;
  if (base >= cnt) return;
  const int me = base + threadIdx.x;
  const bool valid = me < cnt;
  const unsigned long long mykey =
      valid ? g_cand[(size_t)b * CANDN + me] : ~0ull;
  int rank = 0;
  for (int t0 = 0; t0 < cnt; t0 += 256) {
    const int tn = min(256, cnt - t0);
    __syncthreads();
    if (threadIdx.x < tn)
      tile[threadIdx.x] = g_cand[(size_t)b * CANDN + t0 + threadIdx.x];
    __syncthreads();
    for (int j = 0; j < tn; j++)            // broadcast LDS read per iter
      rank += (tile[j] < mykey) ? 1 : 0;
  }
  if (valid && rank < TOPK)
    g_topk[(size_t)b * TOPK + rank] = (unsigned int)(mykey & 0xffffffffu);
}

// Kernel 5: gather boxes; label/dir/score; standup boxes in f64.
__global__ void k_gather(const float* __restrict__ box, const float* __restrict__ cls,
                         const float* __restrict__ dirp) {
  const int b = blockIdx.y;
  const int k = blockIdx.x * 256 + threadIdx.x;
  if (k >= TOPK) return;
  const unsigned int n = g_topk[(size_t)b * TOPK + k];
  const float* bp = box + ((size_t)b * NN + n) * 7;
  float bx[7];
#pragma unroll
  for (int c = 0; c < 7; c++) {
    bx[c] = bp[c];
    g_tb_box[((size_t)b * TOPK + k) * 7 + c] = bx[c];
  }
  const float* cp = cls + ((size_t)b * NN + n) * CC;
  float best = cp[0]; int lab = 0;
#pragma unroll
  for (int c = 1; c < CC; c++) { float v = cp[c]; if (v > best) { best = v; lab = c; } }
  g_tb_score[(size_t)b * TOPK + k] = (float)(1.0 / (1.0 + exp(-(double)best)));
  g_tb_lab[(size_t)b * TOPK + k] = lab;
  const float* dp = dirp + ((size_t)b * NN + n) * 2;
  g_tb_dir[(size_t)b * TOPK + k] = (dp[1] > dp[0]) ? 1 : 0;

  const double cx = bx[0], cy = bx[1], w = bx[3], l = bx[4], ang = bx[6];
  const double c_ = cos(ang), s_ = sin(ang);
  const double hw = 0.5 * w, hl = 0.5 * l;
  double rx0 = (-hw) * c_ - (-hl) * s_ + cx;
  double rx1 = (-hw) * c_ - ( hl) * s_ + cx;
  double rx2 = ( hw) * c_ - ( hl) * s_ + cx;
  double rx3 = ( hw) * c_ - (-hl) * s_ + cx;
  double ry0 = (-hw) * s_ + (-hl) * c_ + cy;
  double ry1 = (-hw) * s_ + ( hl) * c_ + cy;
  double ry2 = ( hw) * s_ + ( hl) * c_ + cy;
  double ry3 = ( hw) * s_ + (-hl) * c_ + cy;
  double x1 = fmin(fmin(rx0, rx1), fmin(rx2, rx3));
  double y1 = fmin(fmin(ry0, ry1), fmin(ry2, ry3));
  double x2 = fmax(fmax(rx0, rx1), fmax(rx2, rx3));
  double y2 = fmax(fmax(ry0, ry1), fmax(ry2, ry3));
  double* sp = g_su + ((size_t)b * TOPK + k) * 4;
  sp[0] = x1; sp[1] = y1; sp[2] = x2; sp[3] = y2;
  g_area[(size_t)b * TOPK + k] = (x2 - x1) * (y2 - y1);
}

// Kernel 6: IoU suppression bitmask (f64).
__global__ void k_nms() {
  const int b = blockIdx.y, i = blockIdx.x;
  const double* sb = g_su + (size_t)b * TOPK * 4;
  const double ix1 = sb[(size_t)i * 4 + 0], iy1 = sb[(size_t)i * 4 + 1];
  const double ix2 = sb[(size_t)i * 4 + 2], iy2 = sb[(size_t)i * 4 + 3];
  const double ai = g_area[(size_t)b * TOPK + i];
  for (int it = 0; it < 4; it++) {
    const int j = it * 256 + threadIdx.x;
    bool pred = false;
    if (j < TOPK && j > i) {
      const double* q = sb + (size_t)j * 4;
      double ltx = fmax(ix1, q[0]), lty = fmax(iy1, q[1]);
      double rbx = fmin(ix2, q[2]), rby = fmin(iy2, q[3]);
      double w = fmax(rbx - ltx, 0.0), h = fmax(rby - lty, 0.0);
      double inter = w * h;
      double iou = inter / (ai + g_area[(size_t)b * TOPK + j] - inter + 1e-8);
      pred = iou > 0.1;
    }
    unsigned long long bal = __ballot(pred);
    if ((threadIdx.x & 63) == 0)
      g_mask[((size_t)b * TOPK + i) * 16 + (unsigned)(j >> 6)] = bal;
  }
}

// Kernel 7: fused greedy scan (wave 0) + float32 output write (all threads).
__global__ __launch_bounds__(256) void k_scanout(float* __restrict__ out, int seg) {
  __shared__ int s_outIdx[PROPN];
  __shared__ int s_cnt;
  const int b = blockIdx.x;
  const int tid = threadIdx.x;
  if (tid < 64) {
    const int lane = tid;
    const unsigned long long* mb = g_mask + (size_t)b * TOPK * 16;
    unsigned long long remv = 0ull;   // lane j<16: accumulated mask word j
    int cnt = 0;
    for (int g = 0; g < 16 && cnt < PROPN; g++) {
      unsigned long long cur = __shfl(remv, g);
      const int rmax = min(64, TOPK - g * 64);
      const unsigned long long vmask =
          (rmax >= 64) ? ~0ull : ((1ull << rmax) - 1ull);
      unsigned long long todo = ~cur & vmask;
      while (todo) {
        const int r = __ffsll((long long)todo) - 1;
        const int i = g * 64 + r;
        if (cnt < PROPN && lane == 0) s_outIdx[cnt] = i;
        cnt++;
        if (cnt >= PROPN) break;
        unsigned long long mw = (lane < 16) ? mb[(size_t)i * 16 + lane] : 0ull;
        remv |= mw;
        cur |= __shfl(mw, g);
        const unsigned long long above = (r >= 63) ? 0ull : (~0ull << (r + 1));
        todo = ~cur & vmask & above;
      }
    }
    if (lane == 0) s_cnt = cnt;
  }
  __syncthreads();
  const int r = tid;
  if (r >= PROPN) return;
  const int K = s_cnt;
  float* boxo = out + ((size_t)b * PROPN + r) * 7;
  float* ido = out + (size_t)seg * 7 + (size_t)b * PROPN + r;
  float* sco = out + (size_t)seg * 8 + (size_t)b * PROPN + r;
  if (r < K) {
    const int i = s_outIdx[r];
    const float* bx = g_tb_box + ((size_t)b * TOPK + i) * 7;
#pragma unroll
    for (int c = 0; c < 6; c++) boxo[c] = bx[c];
    const double period = 3.14159265358979323846;
    double ang = (double)bx[6];
    double rot = ang - floor(ang / period) * period;
    double na = rot + period * (double)g_tb_dir[(size_t)b * TOPK + i];
    boxo[6] = (float)na;
    *ido = (float)g_tb_lab[(size_t)b * TOPK + i];
    *sco = g_tb_score[(size_t)b * TOPK + i];
  } else {
#pragma unroll
    for (int c = 0; c < 7; c++) boxo[c] = 0.0f;
    *ido = 0.0f;
    *sco = 0.0f;
  }
}

extern "C" void kernel_launch(void* const* d_in, const int* in_sizes, int n_in,
                              void* d_out, int out_size, void* d_ws, size_t ws_size,
                              hipStream_t stream) {
  (void)d_ws; (void)ws_size;
  const float* box = nullptr;
  const float* cls = nullptr;
  const float* dirp = nullptr;
  for (int i = 0; i < n_in; i++) {
    long long s = in_sizes[i];
    if (s == (long long)BB * NN * 7) box = (const float*)d_in[i];
    else if (s == (long long)BB * NN * CC) cls = (const float*)d_in[i];
    else if (s == (long long)BB * NN * 2) dirp = (const float*)d_in[i];
  }
  const int seg = out_size / 9;  // = BB*PROPN = 1600

  k_score<<<dim3((NN + SCHUNK - 1) / SCHUNK, BB), 256, 0, stream>>>(cls);
  k_hist<<<dim3((NN + HCHUNK - 1) / HCHUNK, BB), 256, 0, stream>>>();
  k_pickbin<<<BB, 256, 0, stream>>>();
  k_compact<<<dim3((NN + SCHUNK - 1) / SCHUNK, BB), 256, 0, stream>>>();
  k_rank<<<dim3(CANDN / 256, BB), 256, 0, stream>>>();
  k_gather<<<dim3(4, BB), 256, 0, stream>>>(box, cls, dirp);
  k_nms<<<dim3(TOPK, BB), 256, 0, stream>>>();
  k_scanout<<<BB, 256, 0, stream>>>((float*)d_out, seg);
}

// Round 10
// 100.663 us; speedup vs baseline: 1.1268x; 1.1268x over previous
//
#include <hip/hip_runtime.h>
#include <hip/hip_bf16.h>

#define BB 8
#define NN 200000
#define CC 10
#define NBINS 16384
#define TOPK 1000
#define CANDN 4096
#define PROPN 200

// ---- Static device scratch (no dependence on ws_size) ----
__device__ unsigned int g_hist[BB * NBINS];
__device__ int g_candCount[BB];
__device__ unsigned int g_smono[(size_t)BB * NN];   // monotone-mapped scores
__device__ unsigned long long g_cand[BB * CANDN];
__device__ float g_tb_box[BB * TOPK * 7];
__device__ double g_su[BB * TOPK * 4];
__device__ double g_area[BB * TOPK];
__device__ float g_tb_score[BB * TOPK];
__device__ int g_tb_lab[BB * TOPK];
__device__ int g_tb_dir[BB * TOPK];
__device__ unsigned long long g_mask[BB * TOPK * 16];

__device__ __forceinline__ unsigned int f2mono(float f) {
  unsigned int u = __float_as_uint(f);
  return (u & 0x80000000u) ? ~u : (u | 0x80000000u);
}

// Kernel 1: streaming per-box max logit -> monotone u32. Also zeroes
// g_hist / g_candCount at entry (consumers run in later dispatches).
#define SCHUNK 2048
__global__ __launch_bounds__(256) void k_score(const float* __restrict__ cls) {
  {
    const int gid = (blockIdx.y * gridDim.x + blockIdx.x) * 256 + threadIdx.x;
    if (gid < BB * NBINS) g_hist[gid] = 0u;
    if (gid < BB) g_candCount[gid] = 0;
  }
  __shared__ float sb[256 * CC];          // 10 KB staging
  const int b = blockIdx.y;
  const int base = blockIdx.x * SCHUNK;
  const float* cp = cls + ((size_t)b * NN + base) * CC;
  const int nbox = min(SCHUNK, NN - base);
  for (int c0 = 0; c0 < nbox; c0 += 256) {
    const int nb = min(256, nbox - c0);      // 256 or 64 (tail): nb*CC % 4 == 0
    const int nf4 = nb * CC / 4;
    const float4* src = (const float4*)(cp + (size_t)c0 * CC);
    for (int i = threadIdx.x; i < nf4; i += 256)
      ((float4*)sb)[i] = src[i];
    __syncthreads();
    if (threadIdx.x < nb) {
      const float2* p = (const float2*)(sb + threadIdx.x * CC);  // 8B-aligned
      float2 v0 = p[0], v1 = p[1], v2 = p[2], v3 = p[3], v4 = p[4];
      float m = fmaxf(fmaxf(fmaxf(v0.x, v0.y), fmaxf(v1.x, v1.y)),
                      fmaxf(fmaxf(v2.x, v2.y),
                            fmaxf(fmaxf(v3.x, v3.y), fmaxf(v4.x, v4.y))));
      g_smono[(size_t)b * NN + base + c0 + threadIdx.x] = f2mono(m);
    }
    __syncthreads();
  }
}

// Kernel 2: 14-bit-prefix histogram from g_smono (L2-hot, 6.4 MB).
#define HCHUNK 4096
__global__ __launch_bounds__(256) void k_hist() {
  __shared__ unsigned int h[NBINS];       // 64 KB
  for (int i = threadIdx.x; i < NBINS; i += 256) h[i] = 0u;
  __syncthreads();
  const int b = blockIdx.y;
  const int base = blockIdx.x * HCHUNK;
  const int nv = min(HCHUNK, NN - base) / 4;   // all multiples of 4
  const uint4* sp = (const uint4*)(g_smono + (size_t)b * NN + base);
  for (int i = threadIdx.x; i < nv; i += 256) {
    uint4 v = sp[i];
    atomicAdd(&h[v.x >> 18], 1u);
    atomicAdd(&h[v.y >> 18], 1u);
    atomicAdd(&h[v.z >> 18], 1u);
    atomicAdd(&h[v.w >> 18], 1u);
  }
  __syncthreads();
  unsigned int* hg = g_hist + (size_t)b * NBINS;
  for (int i = threadIdx.x; i < NBINS; i += 256)
    if (h[i]) atomicAdd(&hg[i], h[i]);
}

// Kernel 3: fused threshold-bin scan + compaction. Every block recomputes
// binB1 from g_hist (redundant but parallel; deletes the 8-block pickbin
// dispatch), then compacts its chunk with one global atomic per block.
__global__ __launch_bounds__(256) void k_compact() {
  __shared__ unsigned int csum[256];
  __shared__ unsigned long long lbuf[SCHUNK];   // 16 KB
  __shared__ int s_b1, lcnt, lbase;
  const int b = blockIdx.y;
  const unsigned int* h = g_hist + (size_t)b * NBINS;
  {
    unsigned int s = 0;
    const int c0 = threadIdx.x * 64;
    for (int i = 0; i < 64; i++) s += h[c0 + i];
    csum[threadIdx.x] = s;
  }
  if (threadIdx.x == 0) lcnt = 0;
  __syncthreads();
  if (threadIdx.x == 0) {
    unsigned int cum = 0; int bin = 0; bool done = false;
    for (int cc = 255; cc >= 0 && !done; cc--) {
      if (cum + csum[cc] >= (unsigned)TOPK) {
        for (int i = 63; i >= 0; i--) {
          unsigned int v = h[cc * 64 + i];
          if (cum + v >= (unsigned)TOPK) { bin = cc * 64 + i; done = true; break; }
          cum += v;
        }
      } else {
        cum += csum[cc];
      }
    }
    s_b1 = bin;
  }
  __syncthreads();
  const int B1 = s_b1;
  const int base = blockIdx.x * SCHUNK;
  const int lim = min(base + SCHUNK, NN);
  for (int n = base + threadIdx.x; n < lim; n += 256) {
    unsigned int mono = g_smono[(size_t)b * NN + n];
    if ((int)(mono >> 18) >= B1) {
      int p = atomicAdd(&lcnt, 1);
      lbuf[p] = ((unsigned long long)(~mono) << 32) | (unsigned int)n;
    }
  }
  __syncthreads();
  if (threadIdx.x == 0) lbase = atomicAdd(&g_candCount[b], lcnt);
  __syncthreads();
  const int c = lcnt, gb = lbase;
  for (int i = threadIdx.x; i < c; i += 256) {
    int pos = gb + i;
    if (pos < CANDN) g_cand[(size_t)b * CANDN + pos] = lbuf[i];
  }
}

// Kernel 4: fused all-pairs RANK + GATHER. rank(x)=#{keys<x} (keys unique)
// reproduces (score desc, idx asc). A thread with rank<TOPK directly
// gathers box/cls/dir for its idx and writes slot [rank] (g_topk deleted).
__global__ __launch_bounds__(256) void k_rankgather(const float* __restrict__ box,
                                                    const float* __restrict__ cls,
                                                    const float* __restrict__ dirp) {
  __shared__ unsigned long long tile[256];   // 2 KB
  const int b = blockIdx.y;
  const int cnt = min(g_candCount[b], CANDN);
  const int base = blockIdx.x * 256;
  if (base >= cnt) return;                   // block-uniform exit
  const int me = base + threadIdx.x;
  const bool valid = me < cnt;
  const unsigned long long mykey =
      valid ? g_cand[(size_t)b * CANDN + me] : ~0ull;
  int rank = 0;
  for (int t0 = 0; t0 < cnt; t0 += 256) {
    const int tn = min(256, cnt - t0);
    __syncthreads();
    if (threadIdx.x < tn)
      tile[threadIdx.x] = g_cand[(size_t)b * CANDN + t0 + threadIdx.x];
    __syncthreads();
    for (int j = 0; j < tn; j++)            // broadcast LDS read per iter
      rank += (tile[j] < mykey) ? 1 : 0;
  }
  if (!valid || rank >= TOPK) return;       // past all barriers
  const int k = rank;
  const unsigned int n = (unsigned int)(mykey & 0xffffffffu);

  const float* bp = box + ((size_t)b * NN + n) * 7;
  float bx[7];
#pragma unroll
  for (int c = 0; c < 7; c++) {
    bx[c] = bp[c];
    g_tb_box[((size_t)b * TOPK + k) * 7 + c] = bx[c];
  }
  const float* cp = cls + ((size_t)b * NN + n) * CC;
  float best = cp[0]; int lab = 0;
#pragma unroll
  for (int c = 1; c < CC; c++) { float v = cp[c]; if (v > best) { best = v; lab = c; } }
  g_tb_score[(size_t)b * TOPK + k] = (float)(1.0 / (1.0 + exp(-(double)best)));
  g_tb_lab[(size_t)b * TOPK + k] = lab;
  const float* dp = dirp + ((size_t)b * NN + n) * 2;
  g_tb_dir[(size_t)b * TOPK + k] = (dp[1] > dp[0]) ? 1 : 0;

  const double cx = bx[0], cy = bx[1], w = bx[3], l = bx[4], ang = bx[6];
  const double c_ = cos(ang), s_ = sin(ang);
  const double hw = 0.5 * w, hl = 0.5 * l;
  double rx0 = (-hw) * c_ - (-hl) * s_ + cx;
  double rx1 = (-hw) * c_ - ( hl) * s_ + cx;
  double rx2 = ( hw) * c_ - ( hl) * s_ + cx;
  double rx3 = ( hw) * c_ - (-hl) * s_ + cx;
  double ry0 = (-hw) * s_ + (-hl) * c_ + cy;
  double ry1 = (-hw) * s_ + ( hl) * c_ + cy;
  double ry2 = ( hw) * s_ + ( hl) * c_ + cy;
  double ry3 = ( hw) * s_ + (-hl) * c_ + cy;
  double x1 = fmin(fmin(rx0, rx1), fmin(rx2, rx3));
  double y1 = fmin(fmin(ry0, ry1), fmin(ry2, ry3));
  double x2 = fmax(fmax(rx0, rx1), fmax(rx2, rx3));
  double y2 = fmax(fmax(ry0, ry1), fmax(ry2, ry3));
  double* sp = g_su + ((size_t)b * TOPK + k) * 4;
  sp[0] = x1; sp[1] = y1; sp[2] = x2; sp[3] = y2;
  g_area[(size_t)b * TOPK + k] = (x2 - x1) * (y2 - y1);
}

// Kernel 5: IoU suppression bitmask (f64).
__global__ void k_nms() {
  const int b = blockIdx.y, i = blockIdx.x;
  const double* sb = g_su + (size_t)b * TOPK * 4;
  const double ix1 = sb[(size_t)i * 4 + 0], iy1 = sb[(size_t)i * 4 + 1];
  const double ix2 = sb[(size_t)i * 4 + 2], iy2 = sb[(size_t)i * 4 + 3];
  const double ai = g_area[(size_t)b * TOPK + i];
  for (int it = 0; it < 4; it++) {
    const int j = it * 256 + threadIdx.x;
    bool pred = false;
    if (j < TOPK && j > i) {
      const double* q = sb + (size_t)j * 4;
      double ltx = fmax(ix1, q[0]), lty = fmax(iy1, q[1]);
      double rbx = fmin(ix2, q[2]), rby = fmin(iy2, q[3]);
      double w = fmax(rbx - ltx, 0.0), h = fmax(rby - lty, 0.0);
      double inter = w * h;
      double iou = inter / (ai + g_area[(size_t)b * TOPK + j] - inter + 1e-8);
      pred = iou > 0.1;
    }
    unsigned long long bal = __ballot(pred);
    if ((threadIdx.x & 63) == 0)
      g_mask[((size_t)b * TOPK + i) * 16 + (unsigned)(j >> 6)] = bal;
  }
}

// Kernel 6: fused greedy scan (wave 0) + float32 output write (all threads).
__global__ __launch_bounds__(256) void k_scanout(float* __restrict__ out, int seg) {
  __shared__ int s_outIdx[PROPN];
  __shared__ int s_cnt;
  const int b = blockIdx.x;
  const int tid = threadIdx.x;
  if (tid < 64) {
    const int lane = tid;
    const unsigned long long* mb = g_mask + (size_t)b * TOPK * 16;
    unsigned long long remv = 0ull;   // lane j<16: accumulated mask word j
    int cnt = 0;
    for (int g = 0; g < 16 && cnt < PROPN; g++) {
      unsigned long long cur = __shfl(remv, g);
      const int rmax = min(64, TOPK - g * 64);
      const unsigned long long vmask =
          (rmax >= 64) ? ~0ull : ((1ull << rmax) - 1ull);
      unsigned long long todo = ~cur & vmask;
      while (todo) {
        const int r = __ffsll((long long)todo) - 1;
        const int i = g * 64 + r;
        if (cnt < PROPN && lane == 0) s_outIdx[cnt] = i;
        cnt++;
        if (cnt >= PROPN) break;
        unsigned long long mw = (lane < 16) ? mb[(size_t)i * 16 + lane] : 0ull;
        remv |= mw;
        cur |= __shfl(mw, g);
        const unsigned long long above = (r >= 63) ? 0ull : (~0ull << (r + 1));
        todo = ~cur & vmask & above;
      }
    }
    if (lane == 0) s_cnt = cnt;
  }
  __syncthreads();
  const int r = tid;
  if (r >= PROPN) return;
  const int K = s_cnt;
  float* boxo = out + ((size_t)b * PROPN + r) * 7;
  float* ido = out + (size_t)seg * 7 + (size_t)b * PROPN + r;
  float* sco = out + (size_t)seg * 8 + (size_t)b * PROPN + r;
  if (r < K) {
    const int i = s_outIdx[r];
    const float* bx = g_tb_box + ((size_t)b * TOPK + i) * 7;
#pragma unroll
    for (int c = 0; c < 6; c++) boxo[c] = bx[c];
    const double period = 3.14159265358979323846;
    double ang = (double)bx[6];
    double rot = ang - floor(ang / period) * period;
    double na = rot + period * (double)g_tb_dir[(size_t)b * TOPK + i];
    boxo[6] = (float)na;
    *ido = (float)g_tb_lab[(size_t)b * TOPK + i];
    *sco = g_tb_score[(size_t)b * TOPK + i];
  } else {
#pragma unroll
    for (int c = 0; c < 7; c++) boxo[c] = 0.0f;
    *ido = 0.0f;
    *sco = 0.0f;
  }
}

extern "C" void kernel_launch(void* const* d_in, const int* in_sizes, int n_in,
                              void* d_out, int out_size, void* d_ws, size_t ws_size,
                              hipStream_t stream) {
  (void)d_ws; (void)ws_size;
  const float* box = nullptr;
  const float* cls = nullptr;
  const float* dirp = nullptr;
  for (int i = 0; i < n_in; i++) {
    long long s = in_sizes[i];
    if (s == (long long)BB * NN * 7) box = (const float*)d_in[i];
    else if (s == (long long)BB * NN * CC) cls = (const float*)d_in[i];
    else if (s == (long long)BB * NN * 2) dirp = (const float*)d_in[i];
  }
  const int seg = out_size / 9;  // = BB*PROPN = 1600

  k_score<<<dim3((NN + SCHUNK - 1) / SCHUNK, BB), 256, 0, stream>>>(cls);
  k_hist<<<dim3((NN + HCHUNK - 1) / HCHUNK, BB), 256, 0, stream>>>();
  k_compact<<<dim3((NN + SCHUNK - 1) / SCHUNK, BB), 256, 0, stream>>>();
  k_rankgather<<<dim3(CANDN / 256, BB), 256, 0, stream>>>(box, cls, dirp);
  k_nms<<<dim3(TOPK, BB), 256, 0, stream>>>();
  k_scanout<<<BB, 256, 0, stream>>>((float*)d_out, seg);
}

// Round 11
// 96.282 us; speedup vs baseline: 1.1780x; 1.0455x over previous
//
#include <hip/hip_runtime.h>
#include <hip/hip_bf16.h>

#define BB 8
#define NN 200000
#define CC 10
#define NBINS2 8192    // 13-bit monotone prefix (mono >> 19)
#define TOPK 1000
#define CANDN 4096
#define PROPN 200
#define SCHUNK 2048

// ---- Static device scratch (no dependence on ws_size) ----
__device__ unsigned int g_hist[BB * NBINS2];
__device__ int g_candCount[BB];
__device__ unsigned int g_smono[(size_t)BB * NN];   // monotone-mapped scores
__device__ unsigned long long g_cand[BB * CANDN];
__device__ float g_tb_box[BB * TOPK * 7];
__device__ double g_su[BB * TOPK * 4];
__device__ double g_area[BB * TOPK];
__device__ float g_tb_score[BB * TOPK];
__device__ int g_tb_lab[BB * TOPK];
__device__ int g_tb_dir[BB * TOPK];
__device__ unsigned long long g_mask[BB * TOPK * 16];

__device__ __forceinline__ unsigned int f2mono(float f) {
  unsigned int u = __float_as_uint(f);
  return (u & 0x80000000u) ? ~u : (u | 0x80000000u);
}

// Kernel 0: zero histogram + candidate counters (must precede the merge
// in k_scorehist; 256 tiny blocks).
__global__ void k_zero() {
  const int i = blockIdx.x * 256 + threadIdx.x;
  if (i < BB * NBINS2) g_hist[i] = 0u;
  if (i < BB) g_candCount[i] = 0;
}

// Kernel 1: stage-free score + fused LDS histogram.
// Each thread owns 2 boxes = 20 floats = 5x float4 (wave spans 5KB
// contiguous; L1 serves in-wave reuse). No staging LDS, no mid-loop
// barriers. Writes smono as coalesced uint2; merges 32KB LDS hist once.
__global__ __launch_bounds__(256) void k_scorehist(const float* __restrict__ cls) {
  __shared__ unsigned int h[NBINS2];   // 32 KB -> ~5 blocks/CU
  for (int i = threadIdx.x; i < NBINS2; i += 256) h[i] = 0u;
  __syncthreads();
  const int b = blockIdx.y;
  const int base = blockIdx.x * SCHUNK;          // even for all chunks
  const int npair = min(SCHUNK, NN - base) / 2;  // 1024, tail 672
  const float4* cp4 = (const float4*)(cls + ((size_t)b * NN + base) * CC);
  uint2* so = (uint2*)(g_smono + (size_t)b * NN + base);
  for (int p0 = 0; p0 < npair; p0 += 256) {
    const int p = p0 + threadIdx.x;
    if (p < npair) {
      const float4 a0 = cp4[p * 5 + 0], a1 = cp4[p * 5 + 1],
                   a2 = cp4[p * 5 + 2], a3 = cp4[p * 5 + 3],
                   a4 = cp4[p * 5 + 4];
      const float m0 =
          fmaxf(fmaxf(fmaxf(a0.x, a0.y), fmaxf(a0.z, a0.w)),
                fmaxf(fmaxf(a1.x, a1.y), fmaxf(fmaxf(a1.z, a1.w),
                                               fmaxf(a2.x, a2.y))));
      const float m1 =
          fmaxf(fmaxf(fmaxf(a2.z, a2.w), fmaxf(a3.x, a3.y)),
                fmaxf(fmaxf(a3.z, a3.w), fmaxf(fmaxf(a4.x, a4.y),
                                               fmaxf(a4.z, a4.w))));
      const unsigned int mo0 = f2mono(m0), mo1 = f2mono(m1);
      atomicAdd(&h[mo0 >> 19], 1u);
      atomicAdd(&h[mo1 >> 19], 1u);
      so[p] = make_uint2(mo0, mo1);
    }
  }
  __syncthreads();
  unsigned int* hg = g_hist + (size_t)b * NBINS2;
  for (int i = threadIdx.x; i < NBINS2; i += 256)
    if (h[i]) atomicAdd(&hg[i], h[i]);
}

// Kernel 2: fused threshold-bin scan + compaction. Every block recomputes
// binB1 from g_hist (redundant but parallel), then compacts its chunk
// with ONE global atomic per block.
__global__ __launch_bounds__(256) void k_compact() {
  __shared__ unsigned int csum[256];
  __shared__ unsigned long long lbuf[SCHUNK];   // 16 KB
  __shared__ int s_b1, lcnt, lbase;
  const int b = blockIdx.y;
  const unsigned int* h = g_hist + (size_t)b * NBINS2;
  {
    unsigned int s = 0;
    const int c0 = threadIdx.x * 32;             // 8192/256 = 32 bins/thread
    for (int i = 0; i < 32; i++) s += h[c0 + i];
    csum[threadIdx.x] = s;
  }
  if (threadIdx.x == 0) lcnt = 0;
  __syncthreads();
  if (threadIdx.x == 0) {
    unsigned int cum = 0; int bin = 0; bool done = false;
    for (int cc = 255; cc >= 0 && !done; cc--) {
      if (cum + csum[cc] >= (unsigned)TOPK) {
        for (int i = 31; i >= 0; i--) {
          unsigned int v = h[cc * 32 + i];
          if (cum + v >= (unsigned)TOPK) { bin = cc * 32 + i; done = true; break; }
          cum += v;
        }
      } else {
        cum += csum[cc];
      }
    }
    s_b1 = bin;
  }
  __syncthreads();
  const int B1 = s_b1;
  const int base = blockIdx.x * SCHUNK;
  const int lim = min(base + SCHUNK, NN);
  for (int n = base + threadIdx.x; n < lim; n += 256) {
    unsigned int mono = g_smono[(size_t)b * NN + n];
    if ((int)(mono >> 19) >= B1) {
      int p = atomicAdd(&lcnt, 1);
      lbuf[p] = ((unsigned long long)(~mono) << 32) | (unsigned int)n;
    }
  }
  __syncthreads();
  if (threadIdx.x == 0) lbase = atomicAdd(&g_candCount[b], lcnt);
  __syncthreads();
  const int c = lcnt, gb = lbase;
  for (int i = threadIdx.x; i < c; i += 256) {
    int pos = gb + i;
    if (pos < CANDN) g_cand[(size_t)b * CANDN + pos] = lbuf[i];
  }
}

// Kernel 3: fused all-pairs RANK + GATHER. rank(x)=#{keys<x} (keys unique)
// reproduces (score desc, idx asc); rank<TOPK threads gather directly.
__global__ __launch_bounds__(256) void k_rankgather(const float* __restrict__ box,
                                                    const float* __restrict__ cls,
                                                    const float* __restrict__ dirp) {
  __shared__ unsigned long long tile[256];   // 2 KB
  const int b = blockIdx.y;
  const int cnt = min(g_candCount[b], CANDN);
  const int base = blockIdx.x * 256;
  if (base >= cnt) return;                   // block-uniform exit
  const int me = base + threadIdx.x;
  const bool valid = me < cnt;
  const unsigned long long mykey =
      valid ? g_cand[(size_t)b * CANDN + me] : ~0ull;
  int rank = 0;
  for (int t0 = 0; t0 < cnt; t0 += 256) {
    const int tn = min(256, cnt - t0);
    __syncthreads();
    if (threadIdx.x < tn)
      tile[threadIdx.x] = g_cand[(size_t)b * CANDN + t0 + threadIdx.x];
    __syncthreads();
    for (int j = 0; j < tn; j++)            // broadcast LDS read per iter
      rank += (tile[j] < mykey) ? 1 : 0;
  }
  if (!valid || rank >= TOPK) return;       // past all barriers
  const int k = rank;
  const unsigned int n = (unsigned int)(mykey & 0xffffffffu);

  const float* bp = box + ((size_t)b * NN + n) * 7;
  float bx[7];
#pragma unroll
  for (int c = 0; c < 7; c++) {
    bx[c] = bp[c];
    g_tb_box[((size_t)b * TOPK + k) * 7 + c] = bx[c];
  }
  const float* cp = cls + ((size_t)b * NN + n) * CC;
  float best = cp[0]; int lab = 0;
#pragma unroll
  for (int c = 1; c < CC; c++) { float v = cp[c]; if (v > best) { best = v; lab = c; } }
  g_tb_score[(size_t)b * TOPK + k] = (float)(1.0 / (1.0 + exp(-(double)best)));
  g_tb_lab[(size_t)b * TOPK + k] = lab;
  const float* dp = dirp + ((size_t)b * NN + n) * 2;
  g_tb_dir[(size_t)b * TOPK + k] = (dp[1] > dp[0]) ? 1 : 0;

  const double cx = bx[0], cy = bx[1], w = bx[3], l = bx[4], ang = bx[6];
  const double c_ = cos(ang), s_ = sin(ang);
  const double hw = 0.5 * w, hl = 0.5 * l;
  double rx0 = (-hw) * c_ - (-hl) * s_ + cx;
  double rx1 = (-hw) * c_ - ( hl) * s_ + cx;
  double rx2 = ( hw) * c_ - ( hl) * s_ + cx;
  double rx3 = ( hw) * c_ - (-hl) * s_ + cx;
  double ry0 = (-hw) * s_ + (-hl) * c_ + cy;
  double ry1 = (-hw) * s_ + ( hl) * c_ + cy;
  double ry2 = ( hw) * s_ + ( hl) * c_ + cy;
  double ry3 = ( hw) * s_ + (-hl) * c_ + cy;
  double x1 = fmin(fmin(rx0, rx1), fmin(rx2, rx3));
  double y1 = fmin(fmin(ry0, ry1), fmin(ry2, ry3));
  double x2 = fmax(fmax(rx0, rx1), fmax(rx2, rx3));
  double y2 = fmax(fmax(ry0, ry1), fmax(ry2, ry3));
  double* sp = g_su + ((size_t)b * TOPK + k) * 4;
  sp[0] = x1; sp[1] = y1; sp[2] = x2; sp[3] = y2;
  g_area[(size_t)b * TOPK + k] = (x2 - x1) * (y2 - y1);
}

// Kernel 4: IoU suppression bitmask (f64).
__global__ void k_nms() {
  const int b = blockIdx.y, i = blockIdx.x;
  const double* sb = g_su + (size_t)b * TOPK * 4;
  const double ix1 = sb[(size_t)i * 4 + 0], iy1 = sb[(size_t)i * 4 + 1];
  const double ix2 = sb[(size_t)i * 4 + 2], iy2 = sb[(size_t)i * 4 + 3];
  const double ai = g_area[(size_t)b * TOPK + i];
  for (int it = 0; it < 4; it++) {
    const int j = it * 256 + threadIdx.x;
    bool pred = false;
    if (j < TOPK && j > i) {
      const double* q = sb + (size_t)j * 4;
      double ltx = fmax(ix1, q[0]), lty = fmax(iy1, q[1]);
      double rbx = fmin(ix2, q[2]), rby = fmin(iy2, q[3]);
      double w = fmax(rbx - ltx, 0.0), h = fmax(rby - lty, 0.0);
      double inter = w * h;
      double iou = inter / (ai + g_area[(size_t)b * TOPK + j] - inter + 1e-8);
      pred = iou > 0.1;
    }
    unsigned long long bal = __ballot(pred);
    if ((threadIdx.x & 63) == 0)
      g_mask[((size_t)b * TOPK + i) * 16 + (unsigned)(j >> 6)] = bal;
  }
}

// Kernel 5: fused greedy scan (wave 0) + float32 output write (all threads).
__global__ __launch_bounds__(256) void k_scanout(float* __restrict__ out, int seg) {
  __shared__ int s_outIdx[PROPN];
  __shared__ int s_cnt;
  const int b = blockIdx.x;
  const int tid = threadIdx.x;
  if (tid < 64) {
    const int lane = tid;
    const unsigned long long* mb = g_mask + (size_t)b * TOPK * 16;
    unsigned long long remv = 0ull;   // lane j<16: accumulated mask word j
    int cnt = 0;
    for (int g = 0; g < 16 && cnt < PROPN; g++) {
      unsigned long long cur = __shfl(remv, g);
      const int rmax = min(64, TOPK - g * 64);
      const unsigned long long vmask =
          (rmax >= 64) ? ~0ull : ((1ull << rmax) - 1ull);
      unsigned long long todo = ~cur & vmask;
      while (todo) {
        const int r = __ffsll((long long)todo) - 1;
        const int i = g * 64 + r;
        if (cnt < PROPN && lane == 0) s_outIdx[cnt] = i;
        cnt++;
        if (cnt >= PROPN) break;
        unsigned long long mw = (lane < 16) ? mb[(size_t)i * 16 + lane] : 0ull;
        remv |= mw;
        cur |= __shfl(mw, g);
        const unsigned long long above = (r >= 63) ? 0ull : (~0ull << (r + 1));
        todo = ~cur & vmask & above;
      }
    }
    if (lane == 0) s_cnt = cnt;
  }
  __syncthreads();
  const int r = tid;
  if (r >= PROPN) return;
  const int K = s_cnt;
  float* boxo = out + ((size_t)b * PROPN + r) * 7;
  float* ido = out + (size_t)seg * 7 + (size_t)b * PROPN + r;
  float* sco = out + (size_t)seg * 8 + (size_t)b * PROPN + r;
  if (r < K) {
    const int i = s_outIdx[r];
    const float* bx = g_tb_box + ((size_t)b * TOPK + i) * 7;
#pragma unroll
    for (int c = 0; c < 6; c++) boxo[c] = bx[c];
    const double period = 3.14159265358979323846;
    double ang = (double)bx[6];
    double rot = ang - floor(ang / period) * period;
    double na = rot + period * (double)g_tb_dir[(size_t)b * TOPK + i];
    boxo[6] = (float)na;
    *ido = (float)g_tb_lab[(size_t)b * TOPK + i];
    *sco = g_tb_score[(size_t)b * TOPK + i];
  } else {
#pragma unroll
    for (int c = 0; c < 7; c++) boxo[c] = 0.0f;
    *ido = 0.0f;
    *sco = 0.0f;
  }
}

extern "C" void kernel_launch(void* const* d_in, const int* in_sizes, int n_in,
                              void* d_out, int out_size, void* d_ws, size_t ws_size,
                              hipStream_t stream) {
  (void)d_ws; (void)ws_size;
  const float* box = nullptr;
  const float* cls = nullptr;
  const float* dirp = nullptr;
  for (int i = 0; i < n_in; i++) {
    long long s = in_sizes[i];
    if (s == (long long)BB * NN * 7) box = (const float*)d_in[i];
    else if (s == (long long)BB * NN * CC) cls = (const float*)d_in[i];
    else if (s == (long long)BB * NN * 2) dirp = (const float*)d_in[i];
  }
  const int seg = out_size / 9;  // = BB*PROPN = 1600

  k_zero<<<(BB * NBINS2 + 255) / 256, 256, 0, stream>>>();
  k_scorehist<<<dim3((NN + SCHUNK - 1) / SCHUNK, BB), 256, 0, stream>>>(cls);
  k_compact<<<dim3((NN + SCHUNK - 1) / SCHUNK, BB), 256, 0, stream>>>();
  k_rankgather<<<dim3(CANDN / 256, BB), 256, 0, stream>>>(box, cls, dirp);
  k_nms<<<dim3(TOPK, BB), 256, 0, stream>>>();
  k_scanout<<<BB, 256, 0, stream>>>((float*)d_out, seg);
}